// Round 3
// baseline (11021.496 us; speedup 1.0000x reference)
//
#include <hip/hip_runtime.h>
#include <math.h>

// ConvLSTM encoder, MI355X. Batch-persistent: one block per batch element,
// 512 threads (8 waves). All recurrent state on-chip: h0/h1 bf16 in LDS,
// c0/c1 fp32 in registers. Convs = MFMA GEMMs (M=pixels, N=gates*ch,
// K=im2col taps read straight from LDS h-state). Per-wave accumulators
// sized to avoid VGPR spills (R2 failure mode: 5.2 GB scratch traffic).

typedef __bf16 bf16x8 __attribute__((ext_vector_type(8)));
typedef float  f32x4  __attribute__((ext_vector_type(4)));

__device__ __forceinline__ float sigm(float x)  { return 1.f / (1.f + __expf(-x)); }
__device__ __forceinline__ float ftanh(float x) { float e = __expf(2.f * x); return 1.f - 2.f / (e + 1.f); }

// ---------------- workspace layout (bytes) ----------------
#define OFF_WP0  ((size_t)0)          // [128][320] bf16 = 81,920
#define OFF_WP1  ((size_t)81920)      // [256][864] bf16 = 442,368
#define OFF_WFC  ((size_t)524288)     // [168][64][64] bf16 = 1,376,256
#define WS_NEED  ((size_t)1900544)

// ---------------- weight pack kernels ----------------
// Wp0[n][k], n=gate*32+ch (128 rows), K=320: k<32 = im2col-x (ky*6+kx*2+cin,
// zero-padded 18->32); k>=32: (tap*32+c) from Wh0[n][c][tap].
__global__ void pack_w0(const float* __restrict__ wx0, const float* __restrict__ wh0,
                        __bf16* __restrict__ dst) {
  int o = blockIdx.x * 256 + threadIdx.x;
  if (o >= 128 * 320) return;
  int n = o / 320, k = o - n * 320;
  float v = 0.f;
  if (k < 32) {
    if (k < 18) {
      int ky = k / 6, rem = k - ky * 6, kx = rem >> 1, ci = rem & 1;
      v = wx0[(n * 2 + ci) * 9 + ky * 3 + kx];
    }
  } else {
    int tk = k - 32, tap = tk >> 5, c = tk & 31;
    v = wh0[(n * 32 + c) * 9 + tap];
  }
  dst[o] = (__bf16)v;
}

// Wp1[n][k], n=gate*64+ch (256 rows), K=864: k<288: tap*32+c from Wx1 (cin=32);
// k>=288: ((tap*2+half)*32+c) from Wh1[n][half*32+c][tap] (cin=64).
__global__ void pack_w1(const float* __restrict__ wx1, const float* __restrict__ wh1,
                        __bf16* __restrict__ dst) {
  int o = blockIdx.x * 256 + threadIdx.x;
  if (o >= 256 * 864) return;
  int n = o / 864, k = o - n * 864;
  float v;
  if (k < 288) {
    int tap = k >> 5, c = k & 31;
    v = wx1[(n * 32 + c) * 9 + tap];
  } else {
    int tk = k - 288, s2 = tk >> 5, c = tk & 31, tap = s2 >> 1, hf = s2 & 1;
    v = wh1[(n * 64 + hf * 32 + c) * 9 + tap];
  }
  dst[o] = (__bf16)v;
}

// Wfc2[pix][ch][n] bf16 = fc1_w[n][ch*168+pix]
__global__ void pack_wfc(const float* __restrict__ w, __bf16* __restrict__ dst) {
  int o = blockIdx.x * 256 + threadIdx.x;
  if (o >= 168 * 64 * 64) return;
  int pix = o >> 12, ch = (o >> 6) & 63, n = o & 63;
  dst[o] = (__bf16)w[n * 10752 + ch * 168 + pix];
}

// ---------------- the persistent ConvLSTM kernel ----------------
__global__ __launch_bounds__(512, 2) void convlstm_persistent(
    const float* __restrict__ input, const float* __restrict__ x_ex,
    const __bf16* __restrict__ wp0, const __bf16* __restrict__ wp1,
    const __bf16* __restrict__ wfc2,
    const float* __restrict__ bx0, const float* __restrict__ bx1,
    const float* __restrict__ wc0, const float* __restrict__ wc1,
    const float* __restrict__ fc1b,
    const float* __restrict__ exw, const float* __restrict__ exb,
    float* __restrict__ out)
{
  __shared__ __bf16 sh0[9 * 26 * 40];   // h0 padded [y][x][40], ch<32 used
  __shared__ __bf16 sh1[9 * 26 * 72];   // h1 padded [y][x][72], ch<64 used
  __shared__ __bf16 sx2[168 * 32];      // im2col x [pix][32] (chunk-swizzled)

  const int b = blockIdx.x;
  const int t = threadIdx.x;
  const int w = t >> 6, L = t & 63;
  const int lo16 = L & 15, hi4 = L >> 4;

  // ---- zero LDS ----
  {
    int* p0 = (int*)sh0;
    for (int i = t; i < 9 * 26 * 40 / 2; i += 512) p0[i] = 0;
    int* p1 = (int*)sh1;
    for (int i = t; i < 9 * 26 * 72 / 2; i += 512) p1[i] = 0;
    int* p2 = (int*)sx2;
    for (int i = t; i < 168 * 32 / 2; i += 512) p2[i] = 0;
  }
  __syncthreads();

  // ---- build im2col x2 (time-constant), k-chunk XOR-swizzled per pixel ----
  if (t < 168) {
    int iy = t / 24, ix = t - iy * 24;
    int key = (t >> 1) & 3;
    __bf16* dst = sx2 + t * 32;
    for (int ky = 0; ky < 3; ++ky) {
      int y = iy + ky - 1;
      if (y < 0 || y >= 7) continue;
      for (int kx = 0; kx < 3; ++kx) {
        int x = ix + kx - 1;
        if (x < 0 || x >= 24) continue;
        int k0 = ky * 6 + kx * 2;
        dst[(((k0 + 0) >> 3) ^ key) * 8 + ((k0 + 0) & 7)] =
            (__bf16)input[((b * 2 + 0) * 7 + y) * 24 + x];
        dst[(((k0 + 1) >> 3) ^ key) * 8 + ((k0 + 1) & 7)] =
            (__bf16)input[((b * 2 + 1) * 7 + y) * 24 + x];
      }
    }
  }

  // ---- per-wave / per-lane constants ----
  // layer 0: wave = (mq 0..3) x (chh 0..1): M-tiles mq*3.. (3,3,3,2), 16 ch
  // layer 1: wave = (mh 0..1) x (chq 0..3): M-tiles mh*6.. (6,5), 16 ch
  const int mq = w >> 1, chh = w & 1;
  const int mh = w >> 2, chq = w & 3;
  const int nt0 = (mq == 3) ? 2 : 3;
  const int nt1 = (mh == 1) ? 5 : 6;

  int b0h[3], b0x[3];
#pragma unroll
  for (int j = 0; j < 3; ++j) {
    int pr = (mq * 3 + j) * 16 + lo16;
    if (pr > 167) pr = 167;            // dummy rows clamp (masked in epilogue)
    int iy = pr / 24, ix = pr - iy * 24;
    b0h[j] = (iy * 26 + ix) * 40;
    b0x[j] = pr * 32 + ((hi4 ^ ((pr >> 1) & 3)) * 8);
  }
  int b1h0[6], b1h1[6];
#pragma unroll
  for (int j = 0; j < 6; ++j) {
    int pr = (mh * 6 + j) * 16 + lo16;
    if (pr > 167) pr = 167;
    int iy = pr / 24, ix = pr - iy * 24;
    b1h0[j] = (iy * 26 + ix) * 40;
    b1h1[j] = (iy * 26 + ix) * 72;
  }
  const int ch0 = chh * 16 + lo16;     // layer-0 channel (0..31)
  const int ch1 = chq * 16 + lo16;     // layer-1 channel (0..63)
  const float bi0 = bx0[ch0], bf0 = bx0[32 + ch0], bg0 = bx0[64 + ch0], bo0 = bx0[96 + ch0];
  const float bi1 = bx1[ch1], bf1 = bx1[64 + ch1], bg1 = bx1[128 + ch1], bo1 = bx1[192 + ch1];

  const __bf16* w0row[4];
  const __bf16* w1row[4];
#pragma unroll
  for (int g = 0; g < 4; ++g) {
    w0row[g] = wp0 + (size_t)(g * 32 + ch0) * 320 + hi4 * 8;
    w1row[g] = wp1 + (size_t)(g * 64 + ch1) * 864 + hi4 * 8;
  }

  float c0r[3][4], c1r[6][4];
#pragma unroll
  for (int j = 0; j < 3; ++j)
#pragma unroll
    for (int r = 0; r < 4; ++r) c0r[j][r] = 0.f;
#pragma unroll
  for (int j = 0; j < 6; ++j)
#pragma unroll
    for (int r = 0; r < 4; ++r) c1r[j][r] = 0.f;

  __syncthreads();   // x2 + zeroed state visible

  for (int st = 0; st < 7; ++st) {
    // ================= layer 0 =================
    f32x4 a0[4][3];
#pragma unroll
    for (int g = 0; g < 4; ++g)
#pragma unroll
      for (int j = 0; j < 3; ++j) a0[g][j] = (f32x4){0.f, 0.f, 0.f, 0.f};

    bf16x8 bc[4], bn[4];
#pragma unroll
    for (int g = 0; g < 4; ++g) bc[g] = *(const bf16x8*)(w0row[g]);

    for (int s = 0; s < 10; ++s) {
      int sp = (s < 9) ? s + 1 : 9;
#pragma unroll
      for (int g = 0; g < 4; ++g) bn[g] = *(const bf16x8*)(w0row[g] + sp * 32);
      if (s == 0) {
#pragma unroll
        for (int j = 0; j < 3; ++j) {
          if (j < nt0) {
            bf16x8 af = *(const bf16x8*)(sx2 + b0x[j]);
#pragma unroll
            for (int g = 0; g < 4; ++g)
              a0[g][j] = __builtin_amdgcn_mfma_f32_16x16x32_bf16(af, bc[g], a0[g][j], 0, 0, 0);
          }
        }
      } else {
        int tap = s - 1, ky = tap / 3, kx = tap - ky * 3;
        int toff = (ky * 26 + kx) * 40 + hi4 * 8;
#pragma unroll
        for (int j = 0; j < 3; ++j) {
          if (j < nt0) {
            bf16x8 af = *(const bf16x8*)(sh0 + b0h[j] + toff);
#pragma unroll
            for (int g = 0; g < 4; ++g)
              a0[g][j] = __builtin_amdgcn_mfma_f32_16x16x32_bf16(af, bc[g], a0[g][j], 0, 0, 0);
          }
        }
      }
#pragma unroll
      for (int g = 0; g < 4; ++g) bc[g] = bn[g];
    }
    __syncthreads();   // all h0(t-1)/x2 reads done

    // layer-0 epilogue: lane owns (pix = (mq*3+j)*16 + hi4*4 + r, ch0)
#pragma unroll
    for (int j = 0; j < 3; ++j) {
      if (j < nt0) {
#pragma unroll
        for (int r = 0; r < 4; ++r) {
          int p = (mq * 3 + j) * 16 + hi4 * 4 + r;
          if (p < 168) {
            float c = c0r[j][r];
            float gi = a0[0][j][r] + bi0;
            float gf = a0[1][j][r] + bf0;
            float gc = a0[2][j][r] + bg0;
            float go = a0[3][j][r] + bo0;
            float wci = wc0[ch0 * 168 + p];
            float wcf = wc0[5376 + ch0 * 168 + p];
            float wco = wc0[10752 + ch0 * 168 + p];
            float ig = sigm(gi + c * wci);
            float fg = sigm(gf + c * wcf);
            float cn = fg * c + ig * ftanh(gc);
            float og = sigm(go + cn * wco);
            float hn = og * ftanh(cn);
            c0r[j][r] = cn;
            int iy = p / 24, ix = p - iy * 24;
            sh0[((iy + 1) * 26 + ix + 1) * 40 + ch0] = (__bf16)hn;
          }
        }
      }
    }
    __syncthreads();   // h0(t) visible

    // ================= layer 1 =================
    f32x4 a1[4][6];
#pragma unroll
    for (int g = 0; g < 4; ++g)
#pragma unroll
      for (int j = 0; j < 6; ++j) a1[g][j] = (f32x4){0.f, 0.f, 0.f, 0.f};

#pragma unroll
    for (int g = 0; g < 4; ++g) bc[g] = *(const bf16x8*)(w1row[g]);

    for (int s = 0; s < 27; ++s) {
      int sp = (s < 26) ? s + 1 : 26;
#pragma unroll
      for (int g = 0; g < 4; ++g) bn[g] = *(const bf16x8*)(w1row[g] + sp * 32);
      if (s < 9) {
        int ky = s / 3, kx = s - ky * 3;
        int toff = (ky * 26 + kx) * 40 + hi4 * 8;
#pragma unroll
        for (int j = 0; j < 6; ++j) {
          if (j < nt1) {
            bf16x8 af = *(const bf16x8*)(sh0 + b1h0[j] + toff);
#pragma unroll
            for (int g = 0; g < 4; ++g)
              a1[g][j] = __builtin_amdgcn_mfma_f32_16x16x32_bf16(af, bc[g], a1[g][j], 0, 0, 0);
          }
        }
      } else {
        int t2 = s - 9, tap = t2 >> 1, hf = t2 & 1;
        int ky = tap / 3, kx = tap - ky * 3;
        int toff = (ky * 26 + kx) * 72 + hf * 32 + hi4 * 8;
#pragma unroll
        for (int j = 0; j < 6; ++j) {
          if (j < nt1) {
            bf16x8 af = *(const bf16x8*)(sh1 + b1h1[j] + toff);
#pragma unroll
            for (int g = 0; g < 4; ++g)
              a1[g][j] = __builtin_amdgcn_mfma_f32_16x16x32_bf16(af, bc[g], a1[g][j], 0, 0, 0);
          }
        }
      }
#pragma unroll
      for (int g = 0; g < 4; ++g) bc[g] = bn[g];
    }
    __syncthreads();   // all h1(t-1)/h0(t) reads done

    // layer-1 epilogue: lane owns (pix = (mh*6+j)*16 + hi4*4 + r, ch1)
#pragma unroll
    for (int j = 0; j < 6; ++j) {
      if (j < nt1) {
#pragma unroll
        for (int r = 0; r < 4; ++r) {
          int p = (mh * 6 + j) * 16 + hi4 * 4 + r;
          if (p < 168) {
            float c = c1r[j][r];
            float gi = a1[0][j][r] + bi1;
            float gf = a1[1][j][r] + bf1;
            float gc = a1[2][j][r] + bg1;
            float go = a1[3][j][r] + bo1;
            float wci = wc1[ch1 * 168 + p];
            float wcf = wc1[10752 + ch1 * 168 + p];
            float wco = wc1[21504 + ch1 * 168 + p];
            float ig = sigm(gi + c * wci);
            float fg = sigm(gf + c * wcf);
            float cn = fg * c + ig * ftanh(gc);
            float og = sigm(go + cn * wco);
            float hn = og * ftanh(cn);
            c1r[j][r] = cn;
            int iy = p / 24, ix = p - iy * 24;
            sh1[((iy + 1) * 26 + ix + 1) * 72 + ch1] = (__bf16)hn;
          }
        }
      }
    }
    __syncthreads();   // h1(t) visible
  }

  // ================= FC heads (h1 final in sh1) =================
  {
    const int o = t & 7, pg = t >> 3;    // pg 0..63; n-group o*8..o*8+7
    float part[8];
#pragma unroll
    for (int q = 0; q < 8; ++q) part[q] = 0.f;
#pragma unroll
    for (int jj = 0; jj < 3; ++jj) {
      int p = pg + 64 * jj;
      if (p < 168) {
        int iy = p / 24, ix = p - iy * 24;
        const __bf16* hrow = sh1 + ((iy + 1) * 26 + ix + 1) * 72;
        const __bf16* wrow = wfc2 + (size_t)p * 4096 + o * 8;
        for (int ch = 0; ch < 64; ++ch) {
          float hv = (float)hrow[ch];
          bf16x8 wv = *(const bf16x8*)(wrow + ch * 64);
#pragma unroll
          for (int q = 0; q < 8; ++q) part[q] += hv * (float)wv[q];
        }
      }
    }
    float* sacc = (float*)sh0;   // reuse h0 area (16 KB needed, 18.7 KB avail)
    __syncthreads();             // h0 no longer needed
#pragma unroll
    for (int q = 0; q < 8; ++q) sacc[pg * 64 + o * 8 + q] = part[q];
    __syncthreads();
    if (t < 64) {
      float s = fc1b[t];
      for (int pg2 = 0; pg2 < 64; ++pg2) s += sacc[pg2 * 64 + t];
      out[(size_t)b * 128 + t] = fmaxf(s, 0.f);
    } else if (t < 128) {
      int j = t - 64;
      float s = exb[j];
      for (int k = 0; k < 24; ++k) s += x_ex[b * 24 + k] * exw[j * 24 + k];
      out[(size_t)b * 128 + 64 + j] = fmaxf(s, 0.f);
    }
  }
}

// ---------------- launcher ----------------
extern "C" void kernel_launch(void* const* d_in, const int* in_sizes, int n_in,
                              void* d_out, int out_size, void* d_ws, size_t ws_size,
                              hipStream_t stream) {
  const float* input = (const float*)d_in[0];
  const float* x_ex  = (const float*)d_in[1];
  const float* Wx0   = (const float*)d_in[2];
  const float* bx0   = (const float*)d_in[3];
  const float* Wh0   = (const float*)d_in[4];
  const float* Wc0   = (const float*)d_in[5];
  const float* Wx1   = (const float*)d_in[6];
  const float* bx1   = (const float*)d_in[7];
  const float* Wh1   = (const float*)d_in[8];
  const float* Wc1   = (const float*)d_in[9];
  const float* fc1w  = (const float*)d_in[10];
  const float* fc1b  = (const float*)d_in[11];
  const float* exw   = (const float*)d_in[12];
  const float* exb   = (const float*)d_in[13];
  (void)in_sizes; (void)n_in;

  if (ws_size < WS_NEED) {
    hipMemsetAsync(d_out, 0, (size_t)out_size * 4, stream);
    return;
  }

  char* ws = (char*)d_ws;
  __bf16* wp0  = (__bf16*)(ws + OFF_WP0);
  __bf16* wp1  = (__bf16*)(ws + OFF_WP1);
  __bf16* wfc2 = (__bf16*)(ws + OFF_WFC);

  pack_w0<<<160, 256, 0, stream>>>(Wx0, Wh0, wp0);
  pack_w1<<<864, 256, 0, stream>>>(Wx1, Wh1, wp1);
  pack_wfc<<<2688, 256, 0, stream>>>(fc1w, wfc2);

  convlstm_persistent<<<2048, 512, 0, stream>>>(
      input, x_ex, wp0, wp1, wfc2, bx0, bx1, Wc0, Wc1, fc1b, exw, exb,
      (float*)d_out);
}

// Round 4
// 10937.843 us; speedup vs baseline: 1.0076x; 1.0076x over previous
//
#include <hip/hip_runtime.h>
#include <math.h>

// ConvLSTM encoder, MI355X. Batch-persistent: one block per batch element,
// 512 threads (8 waves). All recurrent state on-chip: h0/h1 bf16 in LDS,
// c0/c1 fp32 in registers. Convs = MFMA GEMMs (M=pixels, N=gates*ch,
// K=im2col taps read straight from LDS h-state).
// R3 lesson: __launch_bounds__(512,2) capped VGPR at 128 -> 16 GB spill
// traffic. Here: plain __launch_bounds__(512) (cap 256, live set ~220).

typedef __bf16 bf16x8 __attribute__((ext_vector_type(8)));
typedef float  f32x4  __attribute__((ext_vector_type(4)));

__device__ __forceinline__ float sigm(float x)  { return 1.f / (1.f + __expf(-x)); }
__device__ __forceinline__ float ftanh(float x) { float e = __expf(2.f * x); return 1.f - 2.f / (e + 1.f); }

// ---------------- workspace layout (bytes) ----------------
#define OFF_WP0  ((size_t)0)          // [128][320] bf16 = 81,920
#define OFF_WP1  ((size_t)81920)      // [256][864] bf16 = 442,368
#define OFF_WFC  ((size_t)524288)     // [168][64][64] bf16 = 1,376,256
#define WS_NEED  ((size_t)1900544)

// ---------------- weight pack kernels ----------------
__global__ void pack_w0(const float* __restrict__ wx0, const float* __restrict__ wh0,
                        __bf16* __restrict__ dst) {
  int o = blockIdx.x * 256 + threadIdx.x;
  if (o >= 128 * 320) return;
  int n = o / 320, k = o - n * 320;
  float v = 0.f;
  if (k < 32) {
    if (k < 18) {
      int ky = k / 6, rem = k - ky * 6, kx = rem >> 1, ci = rem & 1;
      v = wx0[(n * 2 + ci) * 9 + ky * 3 + kx];
    }
  } else {
    int tk = k - 32, tap = tk >> 5, c = tk & 31;
    v = wh0[(n * 32 + c) * 9 + tap];
  }
  dst[o] = (__bf16)v;
}

__global__ void pack_w1(const float* __restrict__ wx1, const float* __restrict__ wh1,
                        __bf16* __restrict__ dst) {
  int o = blockIdx.x * 256 + threadIdx.x;
  if (o >= 256 * 864) return;
  int n = o / 864, k = o - n * 864;
  float v;
  if (k < 288) {
    int tap = k >> 5, c = k & 31;
    v = wx1[(n * 32 + c) * 9 + tap];
  } else {
    int tk = k - 288, s2 = tk >> 5, c = tk & 31, tap = s2 >> 1, hf = s2 & 1;
    v = wh1[(n * 64 + hf * 32 + c) * 9 + tap];
  }
  dst[o] = (__bf16)v;
}

// Wfc2[pix][ch][n] bf16 = fc1_w[n][ch*168+pix]
__global__ void pack_wfc(const float* __restrict__ w, __bf16* __restrict__ dst) {
  int o = blockIdx.x * 256 + threadIdx.x;
  if (o >= 168 * 64 * 64) return;
  int pix = o >> 12, ch = (o >> 6) & 63, n = o & 63;
  dst[o] = (__bf16)w[n * 10752 + ch * 168 + pix];
}

// ---------------- the persistent ConvLSTM kernel ----------------
__global__ __launch_bounds__(512) void convlstm_persistent(
    const float* __restrict__ input, const float* __restrict__ x_ex,
    const __bf16* __restrict__ wp0, const __bf16* __restrict__ wp1,
    const __bf16* __restrict__ wfc2,
    const float* __restrict__ bx0, const float* __restrict__ bx1,
    const float* __restrict__ wc0, const float* __restrict__ wc1,
    const float* __restrict__ fc1b,
    const float* __restrict__ exw, const float* __restrict__ exb,
    float* __restrict__ out)
{
  __shared__ __bf16 sh0[9 * 26 * 40];   // h0 padded [y][x][40], ch<32 used
  __shared__ __bf16 sh1[9 * 26 * 72];   // h1 padded [y][x][72], ch<64 used
  __shared__ __bf16 sx2[168 * 32];      // im2col x [pix][32] (chunk-swizzled)

  const int b = blockIdx.x;
  const int t = threadIdx.x;
  const int w = t >> 6, L = t & 63;
  const int lo16 = L & 15, hi4 = L >> 4;

  // ---- zero LDS ----
  {
    int* p0 = (int*)sh0;
    for (int i = t; i < 9 * 26 * 40 / 2; i += 512) p0[i] = 0;
    int* p1 = (int*)sh1;
    for (int i = t; i < 9 * 26 * 72 / 2; i += 512) p1[i] = 0;
    int* p2 = (int*)sx2;
    for (int i = t; i < 168 * 32 / 2; i += 512) p2[i] = 0;
  }
  __syncthreads();

  // ---- build im2col x2 (time-constant), k-chunk XOR-swizzled per pixel ----
  if (t < 168) {
    int iy = t / 24, ix = t - iy * 24;
    int key = (t >> 1) & 3;
    __bf16* dst = sx2 + t * 32;
    for (int ky = 0; ky < 3; ++ky) {
      int y = iy + ky - 1;
      if (y < 0 || y >= 7) continue;
      for (int kx = 0; kx < 3; ++kx) {
        int x = ix + kx - 1;
        if (x < 0 || x >= 24) continue;
        int k0 = ky * 6 + kx * 2;
        dst[(((k0 + 0) >> 3) ^ key) * 8 + ((k0 + 0) & 7)] =
            (__bf16)input[((b * 2 + 0) * 7 + y) * 24 + x];
        dst[(((k0 + 1) >> 3) ^ key) * 8 + ((k0 + 1) & 7)] =
            (__bf16)input[((b * 2 + 1) * 7 + y) * 24 + x];
      }
    }
  }

  // ---- per-wave / per-lane constants ----
  // layer 0: wave = (mq 0..3) x (chh 0..1): M-tiles mq*3.. (3,3,3,2), 16 ch
  // layer 1: wave = (mh 0..1) x (chq 0..3): M-tiles mh*6.. (6,5), 16 ch
  const int mq = w >> 1, chh = w & 1;
  const int mh = w >> 2, chq = w & 3;
  const int nt0 = (mq == 3) ? 2 : 3;
  const int nt1 = (mh == 1) ? 5 : 6;

  int b0h[3], b0x[3];
#pragma unroll
  for (int j = 0; j < 3; ++j) {
    int pr = (mq * 3 + j) * 16 + lo16;
    if (pr > 167) pr = 167;            // dummy rows clamp (masked in epilogue)
    int iy = pr / 24, ix = pr - iy * 24;
    b0h[j] = (iy * 26 + ix) * 40;
    b0x[j] = pr * 32 + ((hi4 ^ ((pr >> 1) & 3)) * 8);
  }
  int b1h0[6], b1h1[6];
#pragma unroll
  for (int j = 0; j < 6; ++j) {
    int pr = (mh * 6 + j) * 16 + lo16;
    if (pr > 167) pr = 167;
    int iy = pr / 24, ix = pr - iy * 24;
    b1h0[j] = (iy * 26 + ix) * 40;
    b1h1[j] = (iy * 26 + ix) * 72;
  }
  const int ch0 = chh * 16 + lo16;     // layer-0 channel (0..31)
  const int ch1 = chq * 16 + lo16;     // layer-1 channel (0..63)

  // single base pointer per layer; per-gate offsets are compile-time consts
  const __bf16* w0base = wp0 + (size_t)ch0 * 320 + hi4 * 8;   // + g*(32*320)
  const __bf16* w1base = wp1 + (size_t)ch1 * 864 + hi4 * 8;   // + g*(64*864)

  float c0r[3][4], c1r[6][4];
#pragma unroll
  for (int j = 0; j < 3; ++j)
#pragma unroll
    for (int r = 0; r < 4; ++r) c0r[j][r] = 0.f;
#pragma unroll
  for (int j = 0; j < 6; ++j)
#pragma unroll
    for (int r = 0; r < 4; ++r) c1r[j][r] = 0.f;

  __syncthreads();   // x2 + zeroed state visible

  for (int st = 0; st < 7; ++st) {
    // ================= layer 0 =================
    f32x4 a0[4][3];
#pragma unroll
    for (int g = 0; g < 4; ++g)
#pragma unroll
      for (int j = 0; j < 3; ++j) a0[g][j] = (f32x4){0.f, 0.f, 0.f, 0.f};

    bf16x8 bc[4], bn[4];
#pragma unroll
    for (int g = 0; g < 4; ++g) bc[g] = *(const bf16x8*)(w0base + g * (32 * 320));

    for (int s = 0; s < 10; ++s) {
      int sp = (s < 9) ? s + 1 : 9;
#pragma unroll
      for (int g = 0; g < 4; ++g)
        bn[g] = *(const bf16x8*)(w0base + g * (32 * 320) + sp * 32);
      if (s == 0) {
#pragma unroll
        for (int j = 0; j < 3; ++j) {
          if (j < nt0) {
            bf16x8 af = *(const bf16x8*)(sx2 + b0x[j]);
#pragma unroll
            for (int g = 0; g < 4; ++g)
              a0[g][j] = __builtin_amdgcn_mfma_f32_16x16x32_bf16(af, bc[g], a0[g][j], 0, 0, 0);
          }
        }
      } else {
        int tap = s - 1, ky = tap / 3, kx = tap - ky * 3;
        int toff = (ky * 26 + kx) * 40 + hi4 * 8;
#pragma unroll
        for (int j = 0; j < 3; ++j) {
          if (j < nt0) {
            bf16x8 af = *(const bf16x8*)(sh0 + b0h[j] + toff);
#pragma unroll
            for (int g = 0; g < 4; ++g)
              a0[g][j] = __builtin_amdgcn_mfma_f32_16x16x32_bf16(af, bc[g], a0[g][j], 0, 0, 0);
          }
        }
      }
#pragma unroll
      for (int g = 0; g < 4; ++g) bc[g] = bn[g];
    }
    __syncthreads();   // all h0(t-1)/x2 reads done

    // layer-0 epilogue: lane owns (pix = (mq*3+j)*16 + hi4*4 + r, ch0)
    {
      const float bi0 = bx0[ch0], bf0 = bx0[32 + ch0];
      const float bg0 = bx0[64 + ch0], bo0 = bx0[96 + ch0];
#pragma unroll
      for (int j = 0; j < 3; ++j) {
        if (j < nt0) {
#pragma unroll
          for (int r = 0; r < 4; ++r) {
            int p = (mq * 3 + j) * 16 + hi4 * 4 + r;
            if (p < 168) {
              float c = c0r[j][r];
              float gi = a0[0][j][r] + bi0;
              float gf = a0[1][j][r] + bf0;
              float gc = a0[2][j][r] + bg0;
              float go = a0[3][j][r] + bo0;
              float wci = wc0[ch0 * 168 + p];
              float wcf = wc0[5376 + ch0 * 168 + p];
              float wco = wc0[10752 + ch0 * 168 + p];
              float ig = sigm(gi + c * wci);
              float fg = sigm(gf + c * wcf);
              float cn = fg * c + ig * ftanh(gc);
              float og = sigm(go + cn * wco);
              float hn = og * ftanh(cn);
              c0r[j][r] = cn;
              int iy = p / 24, ix = p - iy * 24;
              sh0[((iy + 1) * 26 + ix + 1) * 40 + ch0] = (__bf16)hn;
            }
          }
        }
      }
    }
    __syncthreads();   // h0(t) visible

    // ================= layer 1 =================
    f32x4 a1[4][6];
#pragma unroll
    for (int g = 0; g < 4; ++g)
#pragma unroll
      for (int j = 0; j < 6; ++j) a1[g][j] = (f32x4){0.f, 0.f, 0.f, 0.f};

#pragma unroll
    for (int g = 0; g < 4; ++g) bc[g] = *(const bf16x8*)(w1base + g * (64 * 864));

    for (int s = 0; s < 27; ++s) {
      int sp = (s < 26) ? s + 1 : 26;
#pragma unroll
      for (int g = 0; g < 4; ++g)
        bn[g] = *(const bf16x8*)(w1base + g * (64 * 864) + sp * 32);
      if (s < 9) {
        int ky = s / 3, kx = s - ky * 3;
        int toff = (ky * 26 + kx) * 40 + hi4 * 8;
#pragma unroll
        for (int j = 0; j < 6; ++j) {
          if (j < nt1) {
            bf16x8 af = *(const bf16x8*)(sh0 + b1h0[j] + toff);
#pragma unroll
            for (int g = 0; g < 4; ++g)
              a1[g][j] = __builtin_amdgcn_mfma_f32_16x16x32_bf16(af, bc[g], a1[g][j], 0, 0, 0);
          }
        }
      } else {
        int t2 = s - 9, tap = t2 >> 1, hf = t2 & 1;
        int ky = tap / 3, kx = tap - ky * 3;
        int toff = (ky * 26 + kx) * 72 + hf * 32 + hi4 * 8;
#pragma unroll
        for (int j = 0; j < 6; ++j) {
          if (j < nt1) {
            bf16x8 af = *(const bf16x8*)(sh1 + b1h1[j] + toff);
#pragma unroll
            for (int g = 0; g < 4; ++g)
              a1[g][j] = __builtin_amdgcn_mfma_f32_16x16x32_bf16(af, bc[g], a1[g][j], 0, 0, 0);
          }
        }
      }
#pragma unroll
      for (int g = 0; g < 4; ++g) bc[g] = bn[g];
    }
    __syncthreads();   // all h1(t-1)/h0(t) reads done

    // layer-1 epilogue: lane owns (pix = (mh*6+j)*16 + hi4*4 + r, ch1)
    {
      const float bi1 = bx1[ch1], bf1 = bx1[64 + ch1];
      const float bg1 = bx1[128 + ch1], bo1 = bx1[192 + ch1];
#pragma unroll
      for (int j = 0; j < 6; ++j) {
        if (j < nt1) {
#pragma unroll
          for (int r = 0; r < 4; ++r) {
            int p = (mh * 6 + j) * 16 + hi4 * 4 + r;
            if (p < 168) {
              float c = c1r[j][r];
              float gi = a1[0][j][r] + bi1;
              float gf = a1[1][j][r] + bf1;
              float gc = a1[2][j][r] + bg1;
              float go = a1[3][j][r] + bo1;
              float wci = wc1[ch1 * 168 + p];
              float wcf = wc1[10752 + ch1 * 168 + p];
              float wco = wc1[21504 + ch1 * 168 + p];
              float ig = sigm(gi + c * wci);
              float fg = sigm(gf + c * wcf);
              float cn = fg * c + ig * ftanh(gc);
              float og = sigm(go + cn * wco);
              float hn = og * ftanh(cn);
              c1r[j][r] = cn;
              int iy = p / 24, ix = p - iy * 24;
              sh1[((iy + 1) * 26 + ix + 1) * 72 + ch1] = (__bf16)hn;
            }
          }
        }
      }
    }
    __syncthreads();   // h1(t) visible
  }

  // ================= FC heads (h1 final in sh1) =================
  {
    const int o = t & 7, pg = t >> 3;    // pg 0..63; n-group o*8..o*8+7
    float part[8];
#pragma unroll
    for (int q = 0; q < 8; ++q) part[q] = 0.f;
#pragma unroll
    for (int jj = 0; jj < 3; ++jj) {
      int p = pg + 64 * jj;
      if (p < 168) {
        int iy = p / 24, ix = p - iy * 24;
        const __bf16* hrow = sh1 + ((iy + 1) * 26 + ix + 1) * 72;
        const __bf16* wrow = wfc2 + (size_t)p * 4096 + o * 8;
        for (int ch = 0; ch < 64; ++ch) {
          float hv = (float)hrow[ch];
          bf16x8 wv = *(const bf16x8*)(wrow + ch * 64);
#pragma unroll
          for (int q = 0; q < 8; ++q) part[q] += hv * (float)wv[q];
        }
      }
    }
    float* sacc = (float*)sh0;   // reuse h0 area (16 KB needed, 18.7 KB avail)
    __syncthreads();             // h0 no longer needed
#pragma unroll
    for (int q = 0; q < 8; ++q) sacc[pg * 64 + o * 8 + q] = part[q];
    __syncthreads();
    if (t < 64) {
      float s = fc1b[t];
      for (int pg2 = 0; pg2 < 64; ++pg2) s += sacc[pg2 * 64 + t];
      out[(size_t)b * 128 + t] = fmaxf(s, 0.f);
    } else if (t < 128) {
      int j = t - 64;
      float s = exb[j];
      for (int k = 0; k < 24; ++k) s += x_ex[b * 24 + k] * exw[j * 24 + k];
      out[(size_t)b * 128 + 64 + j] = fmaxf(s, 0.f);
    }
  }
}

// ---------------- launcher ----------------
extern "C" void kernel_launch(void* const* d_in, const int* in_sizes, int n_in,
                              void* d_out, int out_size, void* d_ws, size_t ws_size,
                              hipStream_t stream) {
  const float* input = (const float*)d_in[0];
  const float* x_ex  = (const float*)d_in[1];
  const float* Wx0   = (const float*)d_in[2];
  const float* bx0   = (const float*)d_in[3];
  const float* Wh0   = (const float*)d_in[4];
  const float* Wc0   = (const float*)d_in[5];
  const float* Wx1   = (const float*)d_in[6];
  const float* bx1   = (const float*)d_in[7];
  const float* Wh1   = (const float*)d_in[8];
  const float* Wc1   = (const float*)d_in[9];
  const float* fc1w  = (const float*)d_in[10];
  const float* fc1b  = (const float*)d_in[11];
  const float* exw   = (const float*)d_in[12];
  const float* exb   = (const float*)d_in[13];
  (void)in_sizes; (void)n_in;

  if (ws_size < WS_NEED) {
    hipMemsetAsync(d_out, 0, (size_t)out_size * 4, stream);
    return;
  }

  char* ws = (char*)d_ws;
  __bf16* wp0  = (__bf16*)(ws + OFF_WP0);
  __bf16* wp1  = (__bf16*)(ws + OFF_WP1);
  __bf16* wfc2 = (__bf16*)(ws + OFF_WFC);

  pack_w0<<<160, 256, 0, stream>>>(Wx0, Wh0, wp0);
  pack_w1<<<864, 256, 0, stream>>>(Wx1, Wh1, wp1);
  pack_wfc<<<2688, 256, 0, stream>>>(fc1w, wfc2);

  convlstm_persistent<<<2048, 512, 0, stream>>>(
      input, x_ex, wp0, wp1, wfc2, bx0, bx1, Wc0, Wc1, fc1b, exw, exb,
      (float*)d_out);
}

// Round 5
// 6136.652 us; speedup vs baseline: 1.7960x; 1.7824x over previous
//
#include <hip/hip_runtime.h>
#include <math.h>

// ConvLSTM encoder, MI355X. Batch-persistent: one block per batch element,
// 512 threads (8 waves). All recurrent state on-chip: h0/h1 bf16 in LDS,
// c0/c1 fp32 in registers. Convs = MFMA GEMMs (M=pixels, N=gates*ch,
// K=im2col taps read straight from LDS h-state).
// R3/R4 lesson: allocator caps VGPRs at 512-pool / (waves implied by LDS
// occupancy) = 128 -> massive spills. Fix: amdgpu_waves_per_eu(2,2) pins a
// 256-reg budget, and layer-1 is M-split into 2 passes (acc 96 -> 48 regs),
// with pass-0 h-outputs staged in registers until the h1(t-1) reads finish.

typedef __bf16 bf16x8 __attribute__((ext_vector_type(8)));
typedef float  f32x4  __attribute__((ext_vector_type(4)));

__device__ __forceinline__ float sigm(float x)  { return 1.f / (1.f + __expf(-x)); }
__device__ __forceinline__ float ftanh(float x) { float e = __expf(2.f * x); return 1.f - 2.f / (e + 1.f); }

// ---------------- workspace layout (bytes) ----------------
#define OFF_WP0  ((size_t)0)          // [128][320] bf16 = 81,920
#define OFF_WP1  ((size_t)81920)      // [256][864] bf16 = 442,368
#define OFF_WFC  ((size_t)524288)     // [168][64][64] bf16 = 1,376,256
#define WS_NEED  ((size_t)1900544)

// ---------------- weight pack kernels ----------------
__global__ void pack_w0(const float* __restrict__ wx0, const float* __restrict__ wh0,
                        __bf16* __restrict__ dst) {
  int o = blockIdx.x * 256 + threadIdx.x;
  if (o >= 128 * 320) return;
  int n = o / 320, k = o - n * 320;
  float v = 0.f;
  if (k < 32) {
    if (k < 18) {
      int ky = k / 6, rem = k - ky * 6, kx = rem >> 1, ci = rem & 1;
      v = wx0[(n * 2 + ci) * 9 + ky * 3 + kx];
    }
  } else {
    int tk = k - 32, tap = tk >> 5, c = tk & 31;
    v = wh0[(n * 32 + c) * 9 + tap];
  }
  dst[o] = (__bf16)v;
}

__global__ void pack_w1(const float* __restrict__ wx1, const float* __restrict__ wh1,
                        __bf16* __restrict__ dst) {
  int o = blockIdx.x * 256 + threadIdx.x;
  if (o >= 256 * 864) return;
  int n = o / 864, k = o - n * 864;
  float v;
  if (k < 288) {
    int tap = k >> 5, c = k & 31;
    v = wx1[(n * 32 + c) * 9 + tap];
  } else {
    int tk = k - 288, s2 = tk >> 5, c = tk & 31, tap = s2 >> 1, hf = s2 & 1;
    v = wh1[(n * 64 + hf * 32 + c) * 9 + tap];
  }
  dst[o] = (__bf16)v;
}

// Wfc2[pix][ch][n] bf16 = fc1_w[n][ch*168+pix]
__global__ void pack_wfc(const float* __restrict__ w, __bf16* __restrict__ dst) {
  int o = blockIdx.x * 256 + threadIdx.x;
  if (o >= 168 * 64 * 64) return;
  int pix = o >> 12, ch = (o >> 6) & 63, n = o & 63;
  dst[o] = (__bf16)w[n * 10752 + ch * 168 + pix];
}

// ---------------- the persistent ConvLSTM kernel ----------------
__global__
__attribute__((amdgpu_flat_work_group_size(512, 512)))
__attribute__((amdgpu_waves_per_eu(2, 2)))
void convlstm_persistent(
    const float* __restrict__ input, const float* __restrict__ x_ex,
    const __bf16* __restrict__ wp0, const __bf16* __restrict__ wp1,
    const __bf16* __restrict__ wfc2,
    const float* __restrict__ bx0, const float* __restrict__ bx1,
    const float* __restrict__ wc0, const float* __restrict__ wc1,
    const float* __restrict__ fc1b,
    const float* __restrict__ exw, const float* __restrict__ exb,
    float* __restrict__ out)
{
  __shared__ __bf16 sh0[9 * 26 * 40];   // h0 padded [y][x][40], ch<32 used
  __shared__ __bf16 sh1[9 * 26 * 72];   // h1 padded [y][x][72], ch<64 used
  __shared__ __bf16 sx2[168 * 32];      // im2col x [pix][32] (chunk-swizzled)

  const int b = blockIdx.x;
  const int t = threadIdx.x;
  const int w = t >> 6, L = t & 63;
  const int lo16 = L & 15, hi4 = L >> 4;

  // ---- zero LDS ----
  {
    int* p0 = (int*)sh0;
    for (int i = t; i < 9 * 26 * 40 / 2; i += 512) p0[i] = 0;
    int* p1 = (int*)sh1;
    for (int i = t; i < 9 * 26 * 72 / 2; i += 512) p1[i] = 0;
    int* p2 = (int*)sx2;
    for (int i = t; i < 168 * 32 / 2; i += 512) p2[i] = 0;
  }
  __syncthreads();

  // ---- build im2col x2 (time-constant), k-chunk XOR-swizzled per pixel ----
  if (t < 168) {
    int iy = t / 24, ix = t - iy * 24;
    int key = (t >> 1) & 3;
    __bf16* dst = sx2 + t * 32;
    for (int ky = 0; ky < 3; ++ky) {
      int y = iy + ky - 1;
      if (y < 0 || y >= 7) continue;
      for (int kx = 0; kx < 3; ++kx) {
        int x = ix + kx - 1;
        if (x < 0 || x >= 24) continue;
        int k0 = ky * 6 + kx * 2;
        dst[(((k0 + 0) >> 3) ^ key) * 8 + ((k0 + 0) & 7)] =
            (__bf16)input[((b * 2 + 0) * 7 + y) * 24 + x];
        dst[(((k0 + 1) >> 3) ^ key) * 8 + ((k0 + 1) & 7)] =
            (__bf16)input[((b * 2 + 1) * 7 + y) * 24 + x];
      }
    }
  }

  // ---- per-wave / per-lane constants ----
  // layer 0: wave = (mq 0..3) x (chh 0..1): M-tiles mq*3+j (3,3,3,2), 16 ch
  // layer 1: wave = (mp 0..1) x (chq 0..3); per pass p01: tiles p01*6+mp*3+j
  const int mq = w >> 1, chh = w & 1;
  const int mp = w >> 2, chq = w & 3;
  const int nt0 = (mq == 3) ? 2 : 3;

  int b0h[3], b0x[3];
#pragma unroll
  for (int j = 0; j < 3; ++j) {
    int pr = (mq * 3 + j) * 16 + lo16;
    if (pr > 167) pr = 167;            // dummy rows clamp (masked in epilogue)
    int iy = pr / 24, ix = pr - iy * 24;
    b0h[j] = (iy * 26 + ix) * 40;
    b0x[j] = pr * 32 + ((hi4 ^ ((pr >> 1) & 3)) * 8);
  }
  int b1h0[2][3], b1h1[2][3];
#pragma unroll
  for (int p01 = 0; p01 < 2; ++p01) {
#pragma unroll
    for (int j = 0; j < 3; ++j) {
      int pr = (p01 * 6 + mp * 3 + j) * 16 + lo16;
      if (pr > 167) pr = 167;
      int iy = pr / 24, ix = pr - iy * 24;
      b1h0[p01][j] = (iy * 26 + ix) * 40;
      b1h1[p01][j] = (iy * 26 + ix) * 72;
    }
  }
  const int ch0 = chh * 16 + lo16;     // layer-0 channel (0..31)
  const int ch1 = chq * 16 + lo16;     // layer-1 channel (0..63)

  // single base pointer per layer; per-gate offsets are compile-time consts
  const __bf16* w0base = wp0 + (size_t)ch0 * 320 + hi4 * 8;   // + g*(32*320)
  const __bf16* w1base = wp1 + (size_t)ch1 * 864 + hi4 * 8;   // + g*(64*864)

  float c0r[3][4], c1r[2][3][4];
#pragma unroll
  for (int j = 0; j < 3; ++j)
#pragma unroll
    for (int r = 0; r < 4; ++r) c0r[j][r] = 0.f;
#pragma unroll
  for (int p01 = 0; p01 < 2; ++p01)
#pragma unroll
    for (int j = 0; j < 3; ++j)
#pragma unroll
      for (int r = 0; r < 4; ++r) c1r[p01][j][r] = 0.f;

  __syncthreads();   // x2 + zeroed state visible

  for (int st = 0; st < 7; ++st) {
    // ================= layer 0 =================
    {
      f32x4 a0[4][3];
#pragma unroll
      for (int g = 0; g < 4; ++g)
#pragma unroll
        for (int j = 0; j < 3; ++j) a0[g][j] = (f32x4){0.f, 0.f, 0.f, 0.f};

      bf16x8 bc[4], bn[4];
#pragma unroll
      for (int g = 0; g < 4; ++g) bc[g] = *(const bf16x8*)(w0base + g * (32 * 320));

      for (int s = 0; s < 10; ++s) {
        int sp = (s < 9) ? s + 1 : 9;
#pragma unroll
        for (int g = 0; g < 4; ++g)
          bn[g] = *(const bf16x8*)(w0base + g * (32 * 320) + sp * 32);
        if (s == 0) {
#pragma unroll
          for (int j = 0; j < 3; ++j) {
            if (j < nt0) {
              bf16x8 af = *(const bf16x8*)(sx2 + b0x[j]);
#pragma unroll
              for (int g = 0; g < 4; ++g)
                a0[g][j] = __builtin_amdgcn_mfma_f32_16x16x32_bf16(af, bc[g], a0[g][j], 0, 0, 0);
            }
          }
        } else {
          int tap = s - 1, ky = tap / 3, kx = tap - ky * 3;
          int toff = (ky * 26 + kx) * 40 + hi4 * 8;
#pragma unroll
          for (int j = 0; j < 3; ++j) {
            if (j < nt0) {
              bf16x8 af = *(const bf16x8*)(sh0 + b0h[j] + toff);
#pragma unroll
              for (int g = 0; g < 4; ++g)
                a0[g][j] = __builtin_amdgcn_mfma_f32_16x16x32_bf16(af, bc[g], a0[g][j], 0, 0, 0);
            }
          }
        }
#pragma unroll
        for (int g = 0; g < 4; ++g) bc[g] = bn[g];
      }
      __syncthreads();   // all h0(t-1)/x2 reads done

      // layer-0 epilogue: lane owns (pix = (mq*3+j)*16 + hi4*4 + r, ch0)
      const float bi0 = bx0[ch0], bf0 = bx0[32 + ch0];
      const float bg0 = bx0[64 + ch0], bo0 = bx0[96 + ch0];
#pragma unroll
      for (int j = 0; j < 3; ++j) {
        if (j < nt0) {
#pragma unroll
          for (int r = 0; r < 4; ++r) {
            int p = (mq * 3 + j) * 16 + hi4 * 4 + r;
            if (p < 168) {
              float c = c0r[j][r];
              float gi = a0[0][j][r] + bi0;
              float gf = a0[1][j][r] + bf0;
              float gc = a0[2][j][r] + bg0;
              float go = a0[3][j][r] + bo0;
              float wci = wc0[ch0 * 168 + p];
              float wcf = wc0[5376 + ch0 * 168 + p];
              float wco = wc0[10752 + ch0 * 168 + p];
              float ig = sigm(gi + c * wci);
              float fg = sigm(gf + c * wcf);
              float cn = fg * c + ig * ftanh(gc);
              float og = sigm(go + cn * wco);
              float hn = og * ftanh(cn);
              c0r[j][r] = cn;
              int iy = p / 24, ix = p - iy * 24;
              sh0[((iy + 1) * 26 + ix + 1) * 40 + ch0] = (__bf16)hn;
            }
          }
        }
      }
    }
    __syncthreads();   // h0(t) visible

    // ================= layer 1: two M-passes =================
    {
      const float bi1 = bx1[ch1], bf1 = bx1[64 + ch1];
      const float bg1 = bx1[128 + ch1], bo1 = bx1[192 + ch1];
      float hstage[3][4];   // pass-0 h(t) staged in registers until commit

      for (int p01 = 0; p01 < 2; ++p01) {
        const int ntp = (p01 == 1 && mp == 1) ? 2 : 3;  // tile 11 all-dummy
        f32x4 a1[4][3];
#pragma unroll
        for (int g = 0; g < 4; ++g)
#pragma unroll
          for (int j = 0; j < 3; ++j) a1[g][j] = (f32x4){0.f, 0.f, 0.f, 0.f};

        bf16x8 bc[4], bn[4];
#pragma unroll
        for (int g = 0; g < 4; ++g) bc[g] = *(const bf16x8*)(w1base + g * (64 * 864));

        for (int s = 0; s < 27; ++s) {
          int sp = (s < 26) ? s + 1 : 26;
#pragma unroll
          for (int g = 0; g < 4; ++g)
            bn[g] = *(const bf16x8*)(w1base + g * (64 * 864) + sp * 32);
          if (s < 9) {
            int ky = s / 3, kx = s - ky * 3;
            int toff = (ky * 26 + kx) * 40 + hi4 * 8;
#pragma unroll
            for (int j = 0; j < 3; ++j) {
              if (j < ntp) {
                bf16x8 af = *(const bf16x8*)(sh0 + b1h0[p01][j] + toff);
#pragma unroll
                for (int g = 0; g < 4; ++g)
                  a1[g][j] = __builtin_amdgcn_mfma_f32_16x16x32_bf16(af, bc[g], a1[g][j], 0, 0, 0);
              }
            }
          } else {
            int t2 = s - 9, tap = t2 >> 1, hf = t2 & 1;
            int ky = tap / 3, kx = tap - ky * 3;
            int toff = (ky * 26 + kx) * 72 + hf * 32 + hi4 * 8;
#pragma unroll
            for (int j = 0; j < 3; ++j) {
              if (j < ntp) {
                bf16x8 af = *(const bf16x8*)(sh1 + b1h1[p01][j] + toff);
#pragma unroll
                for (int g = 0; g < 4; ++g)
                  a1[g][j] = __builtin_amdgcn_mfma_f32_16x16x32_bf16(af, bc[g], a1[g][j], 0, 0, 0);
              }
            }
          }
#pragma unroll
          for (int g = 0; g < 4; ++g) bc[g] = bn[g];
        }

        if (p01 == 0) {
          // pass-0 epilogue: pixels 0..95, no masking; stage h in registers
#pragma unroll
          for (int j = 0; j < 3; ++j) {
#pragma unroll
            for (int r = 0; r < 4; ++r) {
              int p = (mp * 3 + j) * 16 + hi4 * 4 + r;
              float c = c1r[0][j][r];
              float gi = a1[0][j][r] + bi1;
              float gf = a1[1][j][r] + bf1;
              float gc = a1[2][j][r] + bg1;
              float go = a1[3][j][r] + bo1;
              float wci = wc1[ch1 * 168 + p];
              float wcf = wc1[10752 + ch1 * 168 + p];
              float wco = wc1[21504 + ch1 * 168 + p];
              float ig = sigm(gi + c * wci);
              float fg = sigm(gf + c * wcf);
              float cn = fg * c + ig * ftanh(gc);
              float og = sigm(go + cn * wco);
              c1r[0][j][r] = cn;
              hstage[j][r] = og * ftanh(cn);
            }
          }
        } else {
          __syncthreads();   // all sh1(t-1)/sh0(t) reads (both passes) done

          // commit pass-0 staged h(t)
#pragma unroll
          for (int j = 0; j < 3; ++j) {
#pragma unroll
            for (int r = 0; r < 4; ++r) {
              int p = (mp * 3 + j) * 16 + hi4 * 4 + r;
              int iy = p / 24, ix = p - iy * 24;
              sh1[((iy + 1) * 26 + ix + 1) * 72 + ch1] = (__bf16)hstage[j][r];
            }
          }
          // pass-1 epilogue: pixels 96..167 (mask), write h(t) directly
#pragma unroll
          for (int j = 0; j < 3; ++j) {
            if (j < ntp) {
#pragma unroll
              for (int r = 0; r < 4; ++r) {
                int p = (6 + mp * 3 + j) * 16 + hi4 * 4 + r;
                if (p < 168) {
                  float c = c1r[1][j][r];
                  float gi = a1[0][j][r] + bi1;
                  float gf = a1[1][j][r] + bf1;
                  float gc = a1[2][j][r] + bg1;
                  float go = a1[3][j][r] + bo1;
                  float wci = wc1[ch1 * 168 + p];
                  float wcf = wc1[10752 + ch1 * 168 + p];
                  float wco = wc1[21504 + ch1 * 168 + p];
                  float ig = sigm(gi + c * wci);
                  float fg = sigm(gf + c * wcf);
                  float cn = fg * c + ig * ftanh(gc);
                  float og = sigm(go + cn * wco);
                  float hn = og * ftanh(cn);
                  c1r[1][j][r] = cn;
                  int iy = p / 24, ix = p - iy * 24;
                  sh1[((iy + 1) * 26 + ix + 1) * 72 + ch1] = (__bf16)hn;
                }
              }
            }
          }
        }
      }
    }
    __syncthreads();   // h1(t) visible
  }

  // ================= FC heads (h1 final in sh1) =================
  {
    const int o = t & 7, pg = t >> 3;    // pg 0..63; n-group o*8..o*8+7
    float part[8];
#pragma unroll
    for (int q = 0; q < 8; ++q) part[q] = 0.f;
#pragma unroll
    for (int jj = 0; jj < 3; ++jj) {
      int p = pg + 64 * jj;
      if (p < 168) {
        int iy = p / 24, ix = p - iy * 24;
        const __bf16* hrow = sh1 + ((iy + 1) * 26 + ix + 1) * 72;
        const __bf16* wrow = wfc2 + (size_t)p * 4096 + o * 8;
        for (int ch = 0; ch < 64; ++ch) {
          float hv = (float)hrow[ch];
          bf16x8 wv = *(const bf16x8*)(wrow + ch * 64);
#pragma unroll
          for (int q = 0; q < 8; ++q) part[q] += hv * (float)wv[q];
        }
      }
    }
    float* sacc = (float*)sh0;   // reuse h0 area (16 KB needed, 18.7 KB avail)
    __syncthreads();             // h0 no longer needed
#pragma unroll
    for (int q = 0; q < 8; ++q) sacc[pg * 64 + o * 8 + q] = part[q];
    __syncthreads();
    if (t < 64) {
      float s = fc1b[t];
      for (int pg2 = 0; pg2 < 64; ++pg2) s += sacc[pg2 * 64 + t];
      out[(size_t)b * 128 + t] = fmaxf(s, 0.f);
    } else if (t < 128) {
      int j = t - 64;
      float s = exb[j];
      for (int k = 0; k < 24; ++k) s += x_ex[b * 24 + k] * exw[j * 24 + k];
      out[(size_t)b * 128 + 64 + j] = fmaxf(s, 0.f);
    }
  }
}

// ---------------- launcher ----------------
extern "C" void kernel_launch(void* const* d_in, const int* in_sizes, int n_in,
                              void* d_out, int out_size, void* d_ws, size_t ws_size,
                              hipStream_t stream) {
  const float* input = (const float*)d_in[0];
  const float* x_ex  = (const float*)d_in[1];
  const float* Wx0   = (const float*)d_in[2];
  const float* bx0   = (const float*)d_in[3];
  const float* Wh0   = (const float*)d_in[4];
  const float* Wc0   = (const float*)d_in[5];
  const float* Wx1   = (const float*)d_in[6];
  const float* bx1   = (const float*)d_in[7];
  const float* Wh1   = (const float*)d_in[8];
  const float* Wc1   = (const float*)d_in[9];
  const float* fc1w  = (const float*)d_in[10];
  const float* fc1b  = (const float*)d_in[11];
  const float* exw   = (const float*)d_in[12];
  const float* exb   = (const float*)d_in[13];
  (void)in_sizes; (void)n_in;

  if (ws_size < WS_NEED) {
    hipMemsetAsync(d_out, 0, (size_t)out_size * 4, stream);
    return;
  }

  char* ws = (char*)d_ws;
  __bf16* wp0  = (__bf16*)(ws + OFF_WP0);
  __bf16* wp1  = (__bf16*)(ws + OFF_WP1);
  __bf16* wfc2 = (__bf16*)(ws + OFF_WFC);

  pack_w0<<<160, 256, 0, stream>>>(Wx0, Wh0, wp0);
  pack_w1<<<864, 256, 0, stream>>>(Wx1, Wh1, wp1);
  pack_wfc<<<2688, 256, 0, stream>>>(fc1w, wfc2);

  convlstm_persistent<<<2048, 512, 0, stream>>>(
      input, x_ex, wp0, wp1, wfc2, bx0, bx1, Wc0, Wc1, fc1b, exw, exb,
      (float*)d_out);
}

// Round 6
// 5467.161 us; speedup vs baseline: 2.0159x; 1.1225x over previous
//
#include <hip/hip_runtime.h>
#include <math.h>

// ConvLSTM encoder, MI355X. Batch-persistent: one block per batch element,
// 1024 threads (16 waves). All recurrent state on-chip: h0/h1 bf16 in LDS,
// c0/c1 fp32 in registers. Convs = MFMA GEMMs (M=pixels, N=gates*ch,
// K=im2col taps read straight from LDS h-state).
// R3-R5 lesson: the register allocator budgets VGPRs from a PRE-SPILL LDS
// occupancy heuristic (cap = 512 / waves_per_simd_that_LDS_allows); attrs
// are ignored. So: (a) per-lane live set designed to ~110 regs (1024 thr,
// single-pass l1, no B-prefetch dbuf, unroll-1 K-loops), (b) source LDS
// pushed to 83.6 KB (>81.9) so only 1 block/CU fits -> 4 waves/SIMD -> cap
// 128 -> no spills.

typedef __bf16 bf16x8 __attribute__((ext_vector_type(8)));
typedef __bf16 bf16x4 __attribute__((ext_vector_type(4)));
typedef float  f32x4  __attribute__((ext_vector_type(4)));

__device__ __forceinline__ float sigm(float x)  { return 1.f / (1.f + __expf(-x)); }
__device__ __forceinline__ float ftanh(float x) { float e = __expf(2.f * x); return 1.f - 2.f / (e + 1.f); }

// ---------------- workspace layout (bytes) ----------------
#define OFF_WP0  ((size_t)0)          // [128][320] bf16 = 81,920
#define OFF_WP1  ((size_t)81920)      // [256][864] bf16 = 442,368
#define OFF_WFC  ((size_t)524288)     // [168][64][64] bf16 = 1,376,256
#define WS_NEED  ((size_t)1900544)

// ---------------- weight pack kernels ----------------
// Wp0[n][k], n=gate*32+ch (128 rows), K=320: k<32 = im2col-x (ky*6+kx*2+cin,
// zero-padded 18->32); k>=32: (tap*32+c) from Wh0[n][c][tap].
__global__ void pack_w0(const float* __restrict__ wx0, const float* __restrict__ wh0,
                        __bf16* __restrict__ dst) {
  int o = blockIdx.x * 256 + threadIdx.x;
  if (o >= 128 * 320) return;
  int n = o / 320, k = o - n * 320;
  float v = 0.f;
  if (k < 32) {
    if (k < 18) {
      int ky = k / 6, rem = k - ky * 6, kx = rem >> 1, ci = rem & 1;
      v = wx0[(n * 2 + ci) * 9 + ky * 3 + kx];
    }
  } else {
    int tk = k - 32, tap = tk >> 5, c = tk & 31;
    v = wh0[(n * 32 + c) * 9 + tap];
  }
  dst[o] = (__bf16)v;
}

// Wp1[n][k], n=gate*64+ch (256 rows), K=864: k<288: tap*32+c from Wx1 (cin=32);
// k>=288: ((tap*2+half)*32+c) from Wh1[n][half*32+c][tap] (cin=64).
__global__ void pack_w1(const float* __restrict__ wx1, const float* __restrict__ wh1,
                        __bf16* __restrict__ dst) {
  int o = blockIdx.x * 256 + threadIdx.x;
  if (o >= 256 * 864) return;
  int n = o / 864, k = o - n * 864;
  float v;
  if (k < 288) {
    int tap = k >> 5, c = k & 31;
    v = wx1[(n * 32 + c) * 9 + tap];
  } else {
    int tk = k - 288, s2 = tk >> 5, c = tk & 31, tap = s2 >> 1, hf = s2 & 1;
    v = wh1[(n * 64 + hf * 32 + c) * 9 + tap];
  }
  dst[o] = (__bf16)v;
}

// Wfc2[pix][ch][n] bf16 = fc1_w[n][ch*168+pix]
__global__ void pack_wfc(const float* __restrict__ w, __bf16* __restrict__ dst) {
  int o = blockIdx.x * 256 + threadIdx.x;
  if (o >= 168 * 64 * 64) return;
  int pix = o >> 12, ch = (o >> 6) & 63, n = o & 63;
  dst[o] = (__bf16)w[n * 10752 + ch * 168 + pix];
}

// ---------------- the persistent ConvLSTM kernel ----------------
__global__ __launch_bounds__(1024) void convlstm_persistent(
    const float* __restrict__ input, const float* __restrict__ x_ex,
    const __bf16* __restrict__ wp0, const __bf16* __restrict__ wp1,
    const __bf16* __restrict__ wfc2,
    const float* __restrict__ bx0, const float* __restrict__ bx1,
    const float* __restrict__ wc0, const float* __restrict__ wc1,
    const float* __restrict__ fc1b,
    const float* __restrict__ exw, const float* __restrict__ exb,
    float* __restrict__ out)
{
  __shared__ __bf16 sh0[9 * 26 * 40];   // h0 padded [y][x][40], ch<32 used (18,720 B)
  __shared__ __bf16 sh1[9 * 26 * 72];   // h1 padded [y][x][72], ch<64 used (33,696 B)
  __shared__ __bf16 sx2[168 * 32];      // im2col x [pix][32], chunk-swizzled (10,752 B)
  __shared__ float  sacc[5120];         // FC partials + LDS-occupancy pad (20,480 B)
  // total 83,648 B > 81,920 -> 1 block/CU -> allocator budgets 128 VGPR/lane

  const int b = blockIdx.x;
  const int t = threadIdx.x;
  const int w = t >> 6, L = t & 63;
  const int lo16 = L & 15, hi4 = L >> 4;

  // ---- zero LDS ----
  {
    int* p0 = (int*)sh0;
    for (int i = t; i < 9 * 26 * 40 / 2; i += 1024) p0[i] = 0;
    int* p1 = (int*)sh1;
    for (int i = t; i < 9 * 26 * 72 / 2; i += 1024) p1[i] = 0;
    int* p2 = (int*)sx2;
    for (int i = t; i < 168 * 32 / 2; i += 1024) p2[i] = 0;
  }
  __syncthreads();

  // ---- build im2col x2 (time-constant), k-chunk XOR-swizzled per pixel ----
  if (t < 168) {
    int iy = t / 24, ix = t - iy * 24;
    int key = (t >> 1) & 3;
    __bf16* dst = sx2 + t * 32;
    for (int ky = 0; ky < 3; ++ky) {
      int y = iy + ky - 1;
      if (y < 0 || y >= 7) continue;
      for (int kx = 0; kx < 3; ++kx) {
        int x = ix + kx - 1;
        if (x < 0 || x >= 24) continue;
        int k0 = ky * 6 + kx * 2;
        dst[(((k0 + 0) >> 3) ^ key) * 8 + ((k0 + 0) & 7)] =
            (__bf16)input[((b * 2 + 0) * 7 + y) * 24 + x];
        dst[(((k0 + 1) >> 3) ^ key) * 8 + ((k0 + 1) & 7)] =
            (__bf16)input[((b * 2 + 1) * 7 + y) * 24 + x];
      }
    }
  }

  // ---- per-wave / per-lane constants ----
  // layer 0 (waves 0..7): (mq 0..3) x (chh 0..1); M-tiles mq*3+j (tile 11 dummy)
  // layer 1 (all 16):     (mp 0..3) x (chq 0..3); M-tiles mp*3+j (tile 11 dummy)
  const int mq = (w & 7) >> 1, chh = w & 1;
  const int mp = w >> 2, chq = w & 3;
  const int nt0 = (mq == 3) ? 2 : 3;
  const int ntp = (mp == 3) ? 2 : 3;

  int b0h[3], b0x[3];
#pragma unroll
  for (int j = 0; j < 3; ++j) {
    int pr = (mq * 3 + j) * 16 + lo16;
    if (pr > 167) pr = 167;            // dummy rows clamp (masked in epilogue)
    int iy = pr / 24, ix = pr - iy * 24;
    b0h[j] = (iy * 26 + ix) * 40;
    b0x[j] = pr * 32 + ((hi4 ^ ((pr >> 1) & 3)) * 8);
  }
  int b1h0[3], b1h1[3];
#pragma unroll
  for (int j = 0; j < 3; ++j) {
    int pr = (mp * 3 + j) * 16 + lo16;
    if (pr > 167) pr = 167;
    int iy = pr / 24, ix = pr - iy * 24;
    b1h0[j] = (iy * 26 + ix) * 40;
    b1h1[j] = (iy * 26 + ix) * 72;
  }
  const int ch0 = chh * 16 + lo16;     // layer-0 channel (0..31)
  const int ch1 = chq * 16 + lo16;     // layer-1 channel (0..63)

  const __bf16* w0base = wp0 + (size_t)ch0 * 320 + hi4 * 8;   // + g*(32*320)
  const __bf16* w1base = wp1 + (size_t)ch1 * 864 + hi4 * 8;   // + g*(64*864)

  float c0r[3][4], c1r[3][4];
#pragma unroll
  for (int j = 0; j < 3; ++j)
#pragma unroll
    for (int r = 0; r < 4; ++r) { c0r[j][r] = 0.f; c1r[j][r] = 0.f; }

  __syncthreads();   // x2 + zeroed state visible

#pragma unroll 1
  for (int st = 0; st < 7; ++st) {
    // ================= layer 0 (waves 0..7) =================
    if (w < 8) {
      f32x4 a0[4][3];
#pragma unroll
      for (int g = 0; g < 4; ++g)
#pragma unroll
        for (int j = 0; j < 3; ++j) a0[g][j] = (f32x4){0.f, 0.f, 0.f, 0.f};

      // s = 0: time-constant x chunk
      {
        bf16x8 bc[4];
#pragma unroll
        for (int g = 0; g < 4; ++g) bc[g] = *(const bf16x8*)(w0base + g * 10240);
#pragma unroll
        for (int j = 0; j < 3; ++j) {
          if (j < nt0) {
            bf16x8 af = *(const bf16x8*)(sx2 + b0x[j]);
#pragma unroll
            for (int g = 0; g < 4; ++g)
              a0[g][j] = __builtin_amdgcn_mfma_f32_16x16x32_bf16(af, bc[g], a0[g][j], 0, 0, 0);
          }
        }
      }
#pragma unroll 1
      for (int s = 1; s < 10; ++s) {
        bf16x8 bc[4];
#pragma unroll
        for (int g = 0; g < 4; ++g)
          bc[g] = *(const bf16x8*)(w0base + g * 10240 + s * 32);
        int tap = s - 1, ky = tap / 3, kx = tap - ky * 3;
        int toff = (ky * 26 + kx) * 40 + hi4 * 8;
#pragma unroll
        for (int j = 0; j < 3; ++j) {
          if (j < nt0) {
            bf16x8 af = *(const bf16x8*)(sh0 + b0h[j] + toff);
#pragma unroll
            for (int g = 0; g < 4; ++g)
              a0[g][j] = __builtin_amdgcn_mfma_f32_16x16x32_bf16(af, bc[g], a0[g][j], 0, 0, 0);
          }
        }
      }
      __syncthreads();   // all h0(t-1)/x2 reads done

      // layer-0 epilogue: lane owns (pix = (mq*3+j)*16 + hi4*4 + r, ch0)
      const float bi0 = bx0[ch0], bf0 = bx0[32 + ch0];
      const float bg0 = bx0[64 + ch0], bo0 = bx0[96 + ch0];
#pragma unroll
      for (int j = 0; j < 3; ++j) {
        if (j < nt0) {
#pragma unroll
          for (int r = 0; r < 4; ++r) {
            int p = (mq * 3 + j) * 16 + hi4 * 4 + r;
            if (p < 168) {
              float c = c0r[j][r];
              float gi = a0[0][j][r] + bi0;
              float gf = a0[1][j][r] + bf0;
              float gc = a0[2][j][r] + bg0;
              float go = a0[3][j][r] + bo0;
              float wci = wc0[ch0 * 168 + p];
              float wcf = wc0[5376 + ch0 * 168 + p];
              float wco = wc0[10752 + ch0 * 168 + p];
              float ig = sigm(gi + c * wci);
              float fg = sigm(gf + c * wcf);
              float cn = fg * c + ig * ftanh(gc);
              float og = sigm(go + cn * wco);
              float hn = og * ftanh(cn);
              c0r[j][r] = cn;
              int iy = p / 24, ix = p - iy * 24;
              sh0[((iy + 1) * 26 + ix + 1) * 40 + ch0] = (__bf16)hn;
            }
          }
        }
      }
    } else {
      __syncthreads();   // match wave-0..7 barrier
    }
    __syncthreads();     // h0(t) visible

    // ================= layer 1 (all 16 waves, single pass) =================
    {
      f32x4 a1[4][3];
#pragma unroll
      for (int g = 0; g < 4; ++g)
#pragma unroll
        for (int j = 0; j < 3; ++j) a1[g][j] = (f32x4){0.f, 0.f, 0.f, 0.f};

#pragma unroll 1
      for (int s = 0; s < 27; ++s) {
        bf16x8 bc[4];
#pragma unroll
        for (int g = 0; g < 4; ++g)
          bc[g] = *(const bf16x8*)(w1base + g * 55296 + s * 32);
        if (s < 9) {
          int ky = s / 3, kx = s - ky * 3;
          int toff = (ky * 26 + kx) * 40 + hi4 * 8;
#pragma unroll
          for (int j = 0; j < 3; ++j) {
            if (j < ntp) {
              bf16x8 af = *(const bf16x8*)(sh0 + b1h0[j] + toff);
#pragma unroll
              for (int g = 0; g < 4; ++g)
                a1[g][j] = __builtin_amdgcn_mfma_f32_16x16x32_bf16(af, bc[g], a1[g][j], 0, 0, 0);
            }
          }
        } else {
          int t2 = s - 9, tap = t2 >> 1, hf = t2 & 1;
          int ky = tap / 3, kx = tap - ky * 3;
          int toff = (ky * 26 + kx) * 72 + hf * 32 + hi4 * 8;
#pragma unroll
          for (int j = 0; j < 3; ++j) {
            if (j < ntp) {
              bf16x8 af = *(const bf16x8*)(sh1 + b1h1[j] + toff);
#pragma unroll
              for (int g = 0; g < 4; ++g)
                a1[g][j] = __builtin_amdgcn_mfma_f32_16x16x32_bf16(af, bc[g], a1[g][j], 0, 0, 0);
            }
          }
        }
      }
      __syncthreads();   // all sh1(t-1)/sh0(t) reads done

      // layer-1 epilogue: lane owns (pix = (mp*3+j)*16 + hi4*4 + r, ch1)
      const float bi1 = bx1[ch1], bf1 = bx1[64 + ch1];
      const float bg1 = bx1[128 + ch1], bo1 = bx1[192 + ch1];
#pragma unroll
      for (int j = 0; j < 3; ++j) {
        if (j < ntp) {
#pragma unroll
          for (int r = 0; r < 4; ++r) {
            int p = (mp * 3 + j) * 16 + hi4 * 4 + r;
            if (p < 168) {
              float c = c1r[j][r];
              float gi = a1[0][j][r] + bi1;
              float gf = a1[1][j][r] + bf1;
              float gc = a1[2][j][r] + bg1;
              float go = a1[3][j][r] + bo1;
              float wci = wc1[ch1 * 168 + p];
              float wcf = wc1[10752 + ch1 * 168 + p];
              float wco = wc1[21504 + ch1 * 168 + p];
              float ig = sigm(gi + c * wci);
              float fg = sigm(gf + c * wcf);
              float cn = fg * c + ig * ftanh(gc);
              float og = sigm(go + cn * wco);
              float hn = og * ftanh(cn);
              c1r[j][r] = cn;
              int iy = p / 24, ix = p - iy * 24;
              sh1[((iy + 1) * 26 + ix + 1) * 72 + ch1] = (__bf16)hn;
            }
          }
        }
      }
    }
    __syncthreads();   // h1(t) visible
  }

  // ================= FC heads (h1 final in sh1) =================
  {
    const int o = t & 15, pg = t >> 4;    // o: 4 n's (o*4..); pg 0..63
    float part[4];
#pragma unroll
    for (int q = 0; q < 4; ++q) part[q] = 0.f;
#pragma unroll
    for (int jj = 0; jj < 3; ++jj) {
      int p = pg + 64 * jj;
      if (p < 168) {
        int iy = p / 24, ix = p - iy * 24;
        const __bf16* hrow = sh1 + ((iy + 1) * 26 + ix + 1) * 72;
        const __bf16* wrow = wfc2 + (size_t)p * 4096 + o * 4;
        for (int ch = 0; ch < 64; ++ch) {
          float hv = (float)hrow[ch];
          bf16x4 wv = *(const bf16x4*)(wrow + ch * 64);
#pragma unroll
          for (int q = 0; q < 4; ++q) part[q] += hv * (float)wv[q];
        }
      }
    }
#pragma unroll
    for (int q = 0; q < 4; ++q) sacc[pg * 65 + o * 4 + q] = part[q];
    __syncthreads();
    if (t < 64) {
      float s = fc1b[t];
      for (int pg2 = 0; pg2 < 64; ++pg2) s += sacc[pg2 * 65 + t];
      out[(size_t)b * 128 + t] = fmaxf(s, 0.f);
    } else if (t < 128) {
      int j = t - 64;
      float s = exb[j];
      for (int k = 0; k < 24; ++k) s += x_ex[b * 24 + k] * exw[j * 24 + k];
      out[(size_t)b * 128 + 64 + j] = fmaxf(s, 0.f);
    }
  }
}

// ---------------- launcher ----------------
extern "C" void kernel_launch(void* const* d_in, const int* in_sizes, int n_in,
                              void* d_out, int out_size, void* d_ws, size_t ws_size,
                              hipStream_t stream) {
  const float* input = (const float*)d_in[0];
  const float* x_ex  = (const float*)d_in[1];
  const float* Wx0   = (const float*)d_in[2];
  const float* bx0   = (const float*)d_in[3];
  const float* Wh0   = (const float*)d_in[4];
  const float* Wc0   = (const float*)d_in[5];
  const float* Wx1   = (const float*)d_in[6];
  const float* bx1   = (const float*)d_in[7];
  const float* Wh1   = (const float*)d_in[8];
  const float* Wc1   = (const float*)d_in[9];
  const float* fc1w  = (const float*)d_in[10];
  const float* fc1b  = (const float*)d_in[11];
  const float* exw   = (const float*)d_in[12];
  const float* exb   = (const float*)d_in[13];
  (void)in_sizes; (void)n_in;

  if (ws_size < WS_NEED) {
    hipMemsetAsync(d_out, 0, (size_t)out_size * 4, stream);
    return;
  }

  char* ws = (char*)d_ws;
  __bf16* wp0  = (__bf16*)(ws + OFF_WP0);
  __bf16* wp1  = (__bf16*)(ws + OFF_WP1);
  __bf16* wfc2 = (__bf16*)(ws + OFF_WFC);

  pack_w0<<<160, 256, 0, stream>>>(Wx0, Wh0, wp0);
  pack_w1<<<864, 256, 0, stream>>>(Wx1, Wh1, wp1);
  pack_wfc<<<2688, 256, 0, stream>>>(fc1w, wfc2);

  convlstm_persistent<<<2048, 1024, 0, stream>>>(
      input, x_ex, wp0, wp1, wfc2, bx0, bx1, Wc0, Wc1, fc1b, exw, exb,
      (float*)d_out);
}